// Round 4
// baseline (4795.181 us; speedup 1.0000x reference)
//
#include <hip/hip_runtime.h>
#include <math.h>

#define EPS 1e-5f

// ---------------------------------------------------------------------------
// Deconv + GN stats. 256-thread blocks = 4 fully independent waves.
// Wave owns 64 nodes x 32 couts; lane register tile = 4 nodes x 8 couts.
// Wave-private LDS tiles (XT transposed X, WS = W[k]); NO barriers in the
// tap loop -- same-wave DS ops are in-order, so single-buffered tiles are
// safe (tap-k reads precede tap-k+1 writes in program order).
// Per tap per lane: 1024 FMA vs 96 ds_read_b128 (4/16-lane broadcast) and
// ~24 global loads issued a full tap ahead. W delivery is amortized 10x vs
// the round-2 scalar path (the measured bottleneck).
// ---------------------------------------------------------------------------
__global__ __launch_bounds__(256, 3) void deconv_stats_kernel(
    const float* __restrict__ data, const float* __restrict__ W,
    const int* __restrict__ neigh, const int* __restrict__ batch_id,
    float* __restrict__ out, float* __restrict__ gs1, float* __restrict__ gs2,
    float* __restrict__ gcnt, int N)
{
    __shared__ float XT[4][32][64];   // [wave][ci][local node] : 32 KB
    __shared__ float WS[4][1024];     // [wave][ci*32+co]        : 16 KB
    __shared__ float ls1[256];        // per-(batch,ch) sum h
    __shared__ float ls2[256];        // per-(batch,ch) sum h^2
    __shared__ float lcnt[8];

    const int t  = threadIdx.x;
    const int wv = t >> 6;
    const int ln = t & 63;
    const int ns = ln & 15;           // node slot: nodes ns*4..ns*4+3
    const int cs = ln >> 4;           // cout slot: couts cs*8..cs*8+7
    const int wbase = blockIdx.x * 256 + wv * 64;
    const int myn = wbase + ln;       // staging node (lane gathers this row)
    const long srow = (long)(myn < N ? myn : N - 1) * 27;

    ls1[t] = 0.f;
    ls2[t] = 0.f;
    if (t < 8) lcnt[t] = 0.f;
    __syncthreads();                  // only barrier before the epilogue

    float acc[4][8];
#pragma unroll
    for (int j = 0; j < 4; ++j)
#pragma unroll
        for (int c = 0; c < 8; ++c) acc[j][c] = 0.f;

    float* XTw = &XT[wv][0][0];
    float* WSw = &WS[wv][0];

    // ---- prologue: stage tap 0 ----
    int nbn = neigh[srow + 1];        // neighbor index for tap 1
    {
        const int nb0 = neigh[srow];
        const float4* gp = (const float4*)(data + (size_t)nb0 * 32);
        float4 xg[8];
#pragma unroll
        for (int q = 0; q < 8; ++q) xg[q] = gp[q];
        float wg[16];
#pragma unroll
        for (int j = 0; j < 16; ++j) wg[j] = W[j * 64 + ln];
#pragma unroll
        for (int q = 0; q < 8; ++q) {     // transposed scatter, 2-way banks
            XTw[(4 * q + 0) * 64 + ln] = xg[q].x;
            XTw[(4 * q + 1) * 64 + ln] = xg[q].y;
            XTw[(4 * q + 2) * 64 + ln] = xg[q].z;
            XTw[(4 * q + 3) * 64 + ln] = xg[q].w;
        }
#pragma unroll
        for (int j = 0; j < 16; ++j) WSw[j * 64 + ln] = wg[j];
    }

#pragma unroll 1
    for (int k = 0; k < 27; ++k) {
        // issue global loads for tap k+1 (full tap of compute as cover)
        float4 xg[8];
        float wg[16];
        if (k < 26) {
            const float4* gp = (const float4*)(data + (size_t)nbn * 32);
#pragma unroll
            for (int q = 0; q < 8; ++q) xg[q] = gp[q];
            const float* wp = W + (k + 1) * 1024;
#pragma unroll
            for (int j = 0; j < 16; ++j) wg[j] = wp[j * 64 + ln];
            nbn = neigh[srow + (k + 2 < 27 ? k + 2 : 26)];
        }

        // compute tap k from wave-private LDS
#pragma unroll
        for (int ci = 0; ci < 32; ++ci) {
            const float4 xv = *(const float4*)(XTw + ci * 64 + ns * 4);
            const float4 w0 = *(const float4*)(WSw + ci * 32 + cs * 8);
            const float4 w1 = *(const float4*)(WSw + ci * 32 + cs * 8 + 4);
            const float xs[4] = {xv.x, xv.y, xv.z, xv.w};
            const float ws8[8] = {w0.x, w0.y, w0.z, w0.w,
                                  w1.x, w1.y, w1.z, w1.w};
#pragma unroll
            for (int j = 0; j < 4; ++j)
#pragma unroll
                for (int c = 0; c < 8; ++c)
                    acc[j][c] = fmaf(xs[j], ws8[c], acc[j][c]);
        }

        // stage tap k+1 (in-order DS: safe after this tap's reads)
        if (k < 26) {
#pragma unroll
            for (int q = 0; q < 8; ++q) {
                XTw[(4 * q + 0) * 64 + ln] = xg[q].x;
                XTw[(4 * q + 1) * 64 + ln] = xg[q].y;
                XTw[(4 * q + 2) * 64 + ln] = xg[q].z;
                XTw[(4 * q + 3) * 64 + ln] = xg[q].w;
            }
#pragma unroll
            for (int j = 0; j < 16; ++j) WSw[j * 64 + ln] = wg[j];
        }
    }

    // ---- epilogue: store pre-norm h + GN stats (staggered, 2-way max) ----
#pragma unroll
    for (int j = 0; j < 4; ++j) {
        const int n = wbase + ns * 4 + j;
        if (n < N) {
            float* op = out + (size_t)n * 32 + cs * 8;
            ((float4*)op)[0] = make_float4(acc[j][0], acc[j][1],
                                           acc[j][2], acc[j][3]);
            ((float4*)op)[1] = make_float4(acc[j][4], acc[j][5],
                                           acc[j][6], acc[j][7]);
            const int b = batch_id[n];
#pragma unroll
            for (int cc = 0; cc < 8; ++cc) {
                const int cl = (cc + ns) & 7;        // stagger within group
                const float v = acc[j][cl];
                atomicAdd(&ls1[b * 32 + cs * 8 + cl], v);
                atomicAdd(&ls2[b * 32 + cs * 8 + cl], v * v);
            }
            if (cs == 0) atomicAdd(&lcnt[b], 1.0f);
        }
    }
    __syncthreads();

    {
        float v;
        v = ls1[t]; if (v != 0.f) atomicAdd(&gs1[t], v);
        v = ls2[t]; if (v != 0.f) atomicAdd(&gs2[t], v);
        if (t < 8) { v = lcnt[t]; if (v != 0.f) atomicAdd(&gcnt[t], v); }
    }
}

// ---------------------------------------------------------------------------
// GN finalize + apply + ReLU: thread handles one (node, 4-ch group) quad.
// Groups of 4 channels align exactly with float4 quads (C/G = 4).
// ---------------------------------------------------------------------------
__global__ __launch_bounds__(256) void gn_relu_kernel(
    float* __restrict__ out, const int* __restrict__ batch_id,
    const float* __restrict__ gs1, const float* __restrict__ gs2,
    const float* __restrict__ gcnt, const float* __restrict__ gamma,
    const float* __restrict__ beta, int N)
{
    const int idx = blockIdx.x * 256 + threadIdx.x;
    if (idx >= N * 8) return;
    const int n = idx >> 3;           // node
    const int g = idx & 7;            // group = channel quad
    const int b = batch_id[n];

    const float cnt  = gcnt[b] * 4.0f;          // n_nodes * C/G
    const float icnt = 1.0f / (cnt + EPS);
    const float4 s1 = *(const float4*)(gs1 + b * 32 + g * 4);
    const float4 s2 = *(const float4*)(gs2 + b * 32 + g * 4);
    const float S1 = s1.x + s1.y + s1.z + s1.w;
    const float S2 = s2.x + s2.y + s2.z + s2.w;
    const float m   = S1 * icnt;
    const float var = (S2 - 2.0f * m * S1 + cnt * m * m) * icnt;
    const float istd = rsqrtf(var + EPS);

    const float4 gm4 = *(const float4*)(gamma + g * 4);
    const float4 bt4 = *(const float4*)(beta + g * 4);
    float4 h = *(float4*)(out + (size_t)idx * 4);
    h.x = fmaxf((h.x - m) * istd * gm4.x + bt4.x, 0.f);
    h.y = fmaxf((h.y - m) * istd * gm4.y + bt4.y, 0.f);
    h.z = fmaxf((h.z - m) * istd * gm4.z + bt4.z, 0.f);
    h.w = fmaxf((h.w - m) * istd * gm4.w + bt4.w, 0.f);
    *(float4*)(out + (size_t)idx * 4) = h;
}

// ---------------------------------------------------------------------------
extern "C" void kernel_launch(void* const* d_in, const int* in_sizes, int n_in,
                              void* d_out, int out_size, void* d_ws, size_t ws_size,
                              hipStream_t stream) {
    const float* data     = (const float*)d_in[0];   // [N,32]
    const float* weights  = (const float*)d_in[1];   // [27,32,32]
    const float* gamma    = (const float*)d_in[2];   // [32]
    const float* beta     = (const float*)d_in[3];   // [32]
    const int*   neigh    = (const int*)d_in[4];     // [N,27]
    const int*   batch_id = (const int*)d_in[5];     // [N]
    const int N = in_sizes[0] / 32;
    float* out = (float*)d_out;

    // workspace: gs1[256] gs2[256] gcnt[8]
    float* ws = (float*)d_ws;
    float* gs1  = ws;
    float* gs2  = ws + 256;
    float* gcnt = ws + 512;
    hipMemsetAsync(ws, 0, 520 * sizeof(float), stream);

    const int nblocks = (N + 255) / 256;
    hipLaunchKernelGGL(deconv_stats_kernel, dim3(nblocks), dim3(256), 0, stream,
                       data, weights, neigh, batch_id, out, gs1, gs2, gcnt, N);

    const int n8 = N * 8;
    hipLaunchKernelGGL(gn_relu_kernel, dim3((n8 + 255) / 256), dim3(256), 0,
                       stream, out, batch_id, gs1, gs2, gcnt, gamma, beta, N);
}

// Round 5
// 884.660 us; speedup vs baseline: 5.4204x; 5.4204x over previous
//
#include <hip/hip_runtime.h>
#include <math.h>

#define EPS 1e-5f
#define NPB 256            // nodes per block

// ---------------------------------------------------------------------------
// Deconv + GN stats. Round-0 cooperative 2-barrier structure, bigger tiles.
// Block = 256 threads (4 waves), tile = 256 nodes x 32 couts.
// Lane tile = 4 nodes x 8 couts: per wave per tap 96 ds_read_b128 vs
// 2048 VALU-cyc (round 0 was 64 per 1024 -> LDS-pipe-bound at VALUBusy 38%).
// Staging: thread t gathers node base+t's X row (8 float4) + 1 float4 of W.
// NOTE: no runtime indexing of register arrays anywhere (round-3 lesson:
// acc[j][runtime] demoted acc to scratch -> 16 GB of spill traffic).
// ---------------------------------------------------------------------------
__global__ __launch_bounds__(256, 4) void deconv_stats_kernel(
    const float* __restrict__ data, const float* __restrict__ W,
    const int* __restrict__ neigh, const int* __restrict__ batch_id,
    float* __restrict__ out, float* __restrict__ gs1, float* __restrict__ gs2,
    float* __restrict__ gcnt, int N)
{
    __shared__ float XT[32][NPB];    // [ci][local node] : 32 KB
    __shared__ float WS[32 * 32];    // [ci*32+co]       : 4 KB
    __shared__ float ls1[256];       // per-(batch,ch) sum h
    __shared__ float ls2[256];       // per-(batch,ch) sum h^2
    __shared__ float lcnt[8];

    const int t = threadIdx.x;
    const int base = blockIdx.x * NPB;
    const int ns = t >> 2;           // node slot: nodes ns*4 .. ns*4+3
    const int cs = t & 3;            // cout slot: couts cs*8 .. cs*8+7

    ls1[t] = 0.f;
    ls2[t] = 0.f;
    if (t < 8) lcnt[t] = 0.f;
    // visibility of the zero-init is guaranteed by the tap-loop barriers

    const int sn = base + t;         // node this thread stages
    const long srow = (long)(sn < N ? sn : N - 1) * 27;

    float acc[4][8];
#pragma unroll
    for (int j = 0; j < 4; ++j)
#pragma unroll
        for (int c = 0; c < 8; ++c) acc[j][c] = 0.f;

    // prologue: gather tap 0 (X row + W quad) into registers
    float4 xr[8];
    float4 wr;
    {
        const int ng = neigh[srow];
        const float4* gp = (const float4*)(data + (size_t)ng * 32);
#pragma unroll
        for (int q = 0; q < 8; ++q) xr[q] = gp[q];
        wr = ((const float4*)W)[t];
    }
    int nidx = neigh[srow + 1];

#pragma unroll 1
    for (int k = 0; k < 27; ++k) {
        __syncthreads();             // all waves done reading previous tile
        // stage tap k (transposed X: consecutive lanes -> consecutive addrs)
#pragma unroll
        for (int q = 0; q < 8; ++q) {
            XT[4 * q + 0][t] = xr[q].x;
            XT[4 * q + 1][t] = xr[q].y;
            XT[4 * q + 2][t] = xr[q].z;
            XT[4 * q + 3][t] = xr[q].w;
        }
        ((float4*)WS)[t] = wr;
        __syncthreads();             // tile visible

        // issue gathers for tap k+1 (full tap of compute as latency cover)
        if (k < 26) {
            const float4* gp = (const float4*)(data + (size_t)nidx * 32);
#pragma unroll
            for (int q = 0; q < 8; ++q) xr[q] = gp[q];
            wr = ((const float4*)(W + (k + 1) * 1024))[t];
            nidx = neigh[srow + (k + 2 < 27 ? k + 2 : 26)];
        }

        // compute tap k: 3 ds_read_b128 + 32 FMA per ci
#pragma unroll
        for (int ci = 0; ci < 32; ++ci) {
            const float4 xv = *(const float4*)(&XT[ci][ns * 4]);
            const float4 w0 = *(const float4*)(WS + ci * 32 + cs * 8);
            const float4 w1 = *(const float4*)(WS + ci * 32 + cs * 8 + 4);
            acc[0][0] = fmaf(xv.x, w0.x, acc[0][0]);
            acc[0][1] = fmaf(xv.x, w0.y, acc[0][1]);
            acc[0][2] = fmaf(xv.x, w0.z, acc[0][2]);
            acc[0][3] = fmaf(xv.x, w0.w, acc[0][3]);
            acc[0][4] = fmaf(xv.x, w1.x, acc[0][4]);
            acc[0][5] = fmaf(xv.x, w1.y, acc[0][5]);
            acc[0][6] = fmaf(xv.x, w1.z, acc[0][6]);
            acc[0][7] = fmaf(xv.x, w1.w, acc[0][7]);
            acc[1][0] = fmaf(xv.y, w0.x, acc[1][0]);
            acc[1][1] = fmaf(xv.y, w0.y, acc[1][1]);
            acc[1][2] = fmaf(xv.y, w0.z, acc[1][2]);
            acc[1][3] = fmaf(xv.y, w0.w, acc[1][3]);
            acc[1][4] = fmaf(xv.y, w1.x, acc[1][4]);
            acc[1][5] = fmaf(xv.y, w1.y, acc[1][5]);
            acc[1][6] = fmaf(xv.y, w1.z, acc[1][6]);
            acc[1][7] = fmaf(xv.y, w1.w, acc[1][7]);
            acc[2][0] = fmaf(xv.z, w0.x, acc[2][0]);
            acc[2][1] = fmaf(xv.z, w0.y, acc[2][1]);
            acc[2][2] = fmaf(xv.z, w0.z, acc[2][2]);
            acc[2][3] = fmaf(xv.z, w0.w, acc[2][3]);
            acc[2][4] = fmaf(xv.z, w1.x, acc[2][4]);
            acc[2][5] = fmaf(xv.z, w1.y, acc[2][5]);
            acc[2][6] = fmaf(xv.z, w1.z, acc[2][6]);
            acc[2][7] = fmaf(xv.z, w1.w, acc[2][7]);
            acc[3][0] = fmaf(xv.w, w0.x, acc[3][0]);
            acc[3][1] = fmaf(xv.w, w0.y, acc[3][1]);
            acc[3][2] = fmaf(xv.w, w0.z, acc[3][2]);
            acc[3][3] = fmaf(xv.w, w0.w, acc[3][3]);
            acc[3][4] = fmaf(xv.w, w1.x, acc[3][4]);
            acc[3][5] = fmaf(xv.w, w1.y, acc[3][5]);
            acc[3][6] = fmaf(xv.w, w1.z, acc[3][6]);
            acc[3][7] = fmaf(xv.w, w1.w, acc[3][7]);
        }
    }

    // ---- epilogue: store pre-norm h + GN stats ----
    const int n0 = base + ns * 4;
#pragma unroll
    for (int j = 0; j < 4; ++j) {
        const int n = n0 + j;
        if (n < N) {
            float* op = out + (size_t)n * 32 + cs * 8;
            ((float4*)op)[0] = make_float4(acc[j][0], acc[j][1],
                                           acc[j][2], acc[j][3]);
            ((float4*)op)[1] = make_float4(acc[j][4], acc[j][5],
                                           acc[j][6], acc[j][7]);
        }
    }

    bool fast = (n0 + 3 < N);
    int b0 = 0, b3 = 0;
    if (fast) {
        b0 = batch_id[n0];
        b3 = batch_id[n0 + 3];
        fast = (b0 == b3);
    }
    if (fast) {
        // common case: all 4 nodes in the same octree -> 1 atomic per channel
        float* p1 = ls1 + b0 * 32 + cs * 8;
        float* p2 = ls2 + b0 * 32 + cs * 8;
#pragma unroll
        for (int c = 0; c < 8; ++c) {
            const float v0 = acc[0][c], v1 = acc[1][c];
            const float v2 = acc[2][c], v3 = acc[3][c];
            atomicAdd(p1 + c, (v0 + v1) + (v2 + v3));
            atomicAdd(p2 + c, (v0 * v0 + v1 * v1) + (v2 * v2 + v3 * v3));
        }
        if (cs == 0) atomicAdd(&lcnt[b0], 4.0f);
    } else {
#pragma unroll
        for (int j = 0; j < 4; ++j) {
            const int n = n0 + j;
            if (n < N) {
                const int b = batch_id[n];
                float* p1 = ls1 + b * 32 + cs * 8;
                float* p2 = ls2 + b * 32 + cs * 8;
#pragma unroll
                for (int c = 0; c < 8; ++c) {
                    const float v = acc[j][c];
                    atomicAdd(p1 + c, v);
                    atomicAdd(p2 + c, v * v);
                }
                if (cs == 0) atomicAdd(&lcnt[b], 1.0f);
            }
        }
    }
    __syncthreads();

    {
        float v;
        v = ls1[t]; if (v != 0.f) atomicAdd(&gs1[t], v);
        v = ls2[t]; if (v != 0.f) atomicAdd(&gs2[t], v);
        if (t < 8) { v = lcnt[t]; if (v != 0.f) atomicAdd(&gcnt[t], v); }
    }
}

// ---------------------------------------------------------------------------
// GN finalize + apply + ReLU: thread handles one (node, 4-ch group) quad.
// Groups of 4 channels align exactly with float4 quads (C/G = 4).
// ---------------------------------------------------------------------------
__global__ __launch_bounds__(256) void gn_relu_kernel(
    float* __restrict__ out, const int* __restrict__ batch_id,
    const float* __restrict__ gs1, const float* __restrict__ gs2,
    const float* __restrict__ gcnt, const float* __restrict__ gamma,
    const float* __restrict__ beta, int N)
{
    const int idx = blockIdx.x * 256 + threadIdx.x;
    if (idx >= N * 8) return;
    const int n = idx >> 3;           // node
    const int g = idx & 7;            // group = channel quad
    const int b = batch_id[n];

    const float cnt  = gcnt[b] * 4.0f;          // n_nodes * C/G
    const float icnt = 1.0f / (cnt + EPS);
    const float4 s1 = *(const float4*)(gs1 + b * 32 + g * 4);
    const float4 s2 = *(const float4*)(gs2 + b * 32 + g * 4);
    const float S1 = s1.x + s1.y + s1.z + s1.w;
    const float S2 = s2.x + s2.y + s2.z + s2.w;
    const float m   = S1 * icnt;
    const float var = (S2 - 2.0f * m * S1 + cnt * m * m) * icnt;
    const float istd = rsqrtf(var + EPS);

    const float4 gm4 = *(const float4*)(gamma + g * 4);
    const float4 bt4 = *(const float4*)(beta + g * 4);
    float4 h = *(float4*)(out + (size_t)idx * 4);
    h.x = fmaxf((h.x - m) * istd * gm4.x + bt4.x, 0.f);
    h.y = fmaxf((h.y - m) * istd * gm4.y + bt4.y, 0.f);
    h.z = fmaxf((h.z - m) * istd * gm4.z + bt4.z, 0.f);
    h.w = fmaxf((h.w - m) * istd * gm4.w + bt4.w, 0.f);
    *(float4*)(out + (size_t)idx * 4) = h;
}

// ---------------------------------------------------------------------------
extern "C" void kernel_launch(void* const* d_in, const int* in_sizes, int n_in,
                              void* d_out, int out_size, void* d_ws, size_t ws_size,
                              hipStream_t stream) {
    const float* data     = (const float*)d_in[0];   // [N,32]
    const float* weights  = (const float*)d_in[1];   // [27,32,32]
    const float* gamma    = (const float*)d_in[2];   // [32]
    const float* beta     = (const float*)d_in[3];   // [32]
    const int*   neigh    = (const int*)d_in[4];     // [N,27]
    const int*   batch_id = (const int*)d_in[5];     // [N]
    const int N = in_sizes[0] / 32;
    float* out = (float*)d_out;

    // workspace: gs1[256] gs2[256] gcnt[8]
    float* ws = (float*)d_ws;
    float* gs1  = ws;
    float* gs2  = ws + 256;
    float* gcnt = ws + 512;
    hipMemsetAsync(ws, 0, 520 * sizeof(float), stream);

    const int nblocks = (N + NPB - 1) / NPB;
    hipLaunchKernelGGL(deconv_stats_kernel, dim3(nblocks), dim3(256), 0, stream,
                       data, weights, neigh, batch_id, out, gs1, gs2, gcnt, N);

    const int n8 = N * 8;
    hipLaunchKernelGGL(gn_relu_kernel, dim3((n8 + 255) / 256), dim3(256), 0,
                       stream, out, batch_id, gs1, gs2, gcnt, gamma, beta, N);
}

// Round 6
// 323.791 us; speedup vs baseline: 14.8095x; 2.7322x over previous
//
#include <hip/hip_runtime.h>
#include <math.h>

#define EPS 1e-5f

typedef __attribute__((ext_vector_type(8)))  short  short8;   // 8 bf16 (4 VGPR)
typedef __attribute__((ext_vector_type(16))) float  floatx16; // MFMA 32x32 acc

// bf16 round-to-nearest-even helpers (bit-level, no type friction)
__device__ __forceinline__ unsigned short f2bf(float f) {
    unsigned int u = __float_as_uint(f);
    unsigned int r = (u + 0x7FFFu + ((u >> 16) & 1u)) >> 16;
    return (unsigned short)r;
}
__device__ __forceinline__ float bf2f(unsigned short h) {
    return __uint_as_float(((unsigned int)h) << 16);
}

// ---------------------------------------------------------------------------
// Prepass A: data[N][32] fp32 -> dpk[N][64] bf16 rows: [hi ci0..31 | lo ci0..31]
// one thread per 4 elements
// ---------------------------------------------------------------------------
__global__ __launch_bounds__(256) void pack_data_kernel(
    const float* __restrict__ data, unsigned short* __restrict__ dpk, int N)
{
    const int e4 = blockIdx.x * 256 + threadIdx.x;   // float4 index
    if (e4 >= N * 8) return;
    const float4 v = ((const float4*)data)[e4];
    const int node = e4 >> 3;
    const int cq   = (e4 & 7) * 4;                   // ci base
    ushort4 hi, lo;
    hi.x = f2bf(v.x); lo.x = f2bf(v.x - bf2f(hi.x));
    hi.y = f2bf(v.y); lo.y = f2bf(v.y - bf2f(hi.y));
    hi.z = f2bf(v.z); lo.z = f2bf(v.z - bf2f(hi.z));
    hi.w = f2bf(v.w); lo.w = f2bf(v.w - bf2f(hi.w));
    unsigned short* row = dpk + (size_t)node * 64;
    *(ushort4*)(row + cq)      = hi;
    *(ushort4*)(row + 32 + cq) = lo;
}

// ---------------------------------------------------------------------------
// Prepass B: W[27][32][32] -> B-fragments in MFMA lane order.
// For v_mfma_f32_32x32x16_bf16: B[k][n], lane l: n=l&31, k=8*(l>>5)+j.
// whi/wlo layout: [tap][khalf][lane][8] bf16.  thread = one (tap,khalf,lane).
// ---------------------------------------------------------------------------
__global__ __launch_bounds__(256) void pack_w_kernel(
    const float* __restrict__ W, unsigned short* __restrict__ whi,
    unsigned short* __restrict__ wlo)
{
    const int t = blockIdx.x * 256 + threadIdx.x;
    if (t >= 27 * 2 * 64) return;
    const int l  = t & 63;
    const int h  = (t >> 6) & 1;
    const int k  = t >> 7;
    const int n  = l & 31;
    const int cb = h * 16 + (l >> 5) * 8;            // ci base for this lane
    ushort4 h0, h1, l0, l1;
    const float* wp = W + k * 1024 + n;
    float w0 = wp[(cb + 0) * 32], w1 = wp[(cb + 1) * 32];
    float w2 = wp[(cb + 2) * 32], w3 = wp[(cb + 3) * 32];
    float w4 = wp[(cb + 4) * 32], w5 = wp[(cb + 5) * 32];
    float w6 = wp[(cb + 6) * 32], w7 = wp[(cb + 7) * 32];
    h0.x = f2bf(w0); l0.x = f2bf(w0 - bf2f(h0.x));
    h0.y = f2bf(w1); l0.y = f2bf(w1 - bf2f(h0.y));
    h0.z = f2bf(w2); l0.z = f2bf(w2 - bf2f(h0.z));
    h0.w = f2bf(w3); l0.w = f2bf(w3 - bf2f(h0.w));
    h1.x = f2bf(w4); l1.x = f2bf(w4 - bf2f(h1.x));
    h1.y = f2bf(w5); l1.y = f2bf(w5 - bf2f(h1.y));
    h1.z = f2bf(w6); l1.z = f2bf(w6 - bf2f(h1.z));
    h1.w = f2bf(w7); l1.w = f2bf(w7 - bf2f(h1.w));
    *(ushort4*)(whi + (size_t)t * 8)     = h0;
    *(ushort4*)(whi + (size_t)t * 8 + 4) = h1;
    *(ushort4*)(wlo + (size_t)t * 8)     = l0;
    *(ushort4*)(wlo + (size_t)t * 8 + 4) = l1;
}

// ---------------------------------------------------------------------------
// Deconv via MFMA + GN stats. Block = 256 threads = 4 independent waves.
// Wave tile = 32 nodes x 32 couts (one 32x32 accumulator).
// A-frag: lane l holds x[node = wbase+(l&31)][ci = 8*(l>>5)+j (+16 for khalf1)]
//   = one 16 B load straight from the gathered dpk row. No LDS, no barriers.
// 3-term hi/lo product -> fp32-class accuracy. No runtime-indexed reg arrays.
// ---------------------------------------------------------------------------
__global__ __launch_bounds__(256) void deconv_stats_kernel(
    const unsigned short* __restrict__ dpk, const unsigned short* __restrict__ whi,
    const unsigned short* __restrict__ wlo, const int* __restrict__ neigh,
    const int* __restrict__ batch_id, float* __restrict__ out,
    float* __restrict__ gs1, float* __restrict__ gs2, float* __restrict__ gcnt,
    int N)
{
    __shared__ float ls1[256];
    __shared__ float ls2[256];
    __shared__ float lcnt[8];

    const int t    = threadIdx.x;
    const int wv   = t >> 6;
    const int l    = t & 63;
    const int mrow = l & 31;
    const int half = l >> 5;
    const int wbase = blockIdx.x * 128 + wv * 32;
    const int node  = wbase + mrow;
    const int nc    = node < N ? node : N - 1;
    const long srow = (long)nc * 27;

    ls1[t] = 0.f;
    ls2[t] = 0.f;
    if (t < 8) lcnt[t] = 0.f;
    __syncthreads();

    floatx16 acc;
#pragma unroll
    for (int r = 0; r < 16; ++r) acc[r] = 0.f;

    int nidx = neigh[srow];

#pragma unroll 1
    for (int k = 0; k < 27; ++k) {
        const unsigned short* arow = dpk + (size_t)nidx * 64;
        const short8 a_h0 = *(const short8*)(arow + half * 8);        // hi, ci 0-15
        const short8 a_h1 = *(const short8*)(arow + 16 + half * 8);   // hi, ci 16-31
        const short8 a_l0 = *(const short8*)(arow + 32 + half * 8);   // lo, ci 0-15
        const short8 a_l1 = *(const short8*)(arow + 48 + half * 8);   // lo, ci 16-31
        const unsigned short* bb = whi + ((size_t)k * 128 + l) * 8;
        const unsigned short* bl = wlo + ((size_t)k * 128 + l) * 8;
        const short8 b_h0 = *(const short8*)(bb);
        const short8 b_h1 = *(const short8*)(bb + 512);               // khalf1: +64 lanes*8
        const short8 b_l0 = *(const short8*)(bl);
        const short8 b_l1 = *(const short8*)(bl + 512);
        if (k < 26) nidx = neigh[srow + k + 1];

        acc = __builtin_amdgcn_mfma_f32_32x32x16_bf16(a_h0, b_h0, acc, 0, 0, 0);
        acc = __builtin_amdgcn_mfma_f32_32x32x16_bf16(a_h1, b_h1, acc, 0, 0, 0);
        acc = __builtin_amdgcn_mfma_f32_32x32x16_bf16(a_l0, b_h0, acc, 0, 0, 0);
        acc = __builtin_amdgcn_mfma_f32_32x32x16_bf16(a_l1, b_h1, acc, 0, 0, 0);
        acc = __builtin_amdgcn_mfma_f32_32x32x16_bf16(a_h0, b_l0, acc, 0, 0, 0);
        acc = __builtin_amdgcn_mfma_f32_32x32x16_bf16(a_h1, b_l1, acc, 0, 0, 0);
    }

    // ---- epilogue: C layout col=lane&31, row=(reg&3)+8*(reg>>2)+4*(lane>>5) ----
    const int co = mrow;
#pragma unroll
    for (int r = 0; r < 16; ++r) {
        const int row = (r & 3) + 8 * (r >> 2) + 4 * half;
        const int n = wbase + row;
        if (n < N) out[(size_t)n * 32 + co] = acc[r];
    }

    // GN stats
    bool fast = (wbase + 31 < N);
    int bfst = 0;
    if (fast) {
        bfst = batch_id[wbase];
        fast = (bfst == batch_id[wbase + 31]);
    }
    if (fast) {
        float s1 = 0.f, s2 = 0.f;
#pragma unroll
        for (int r = 0; r < 16; ++r) {
            const float v = acc[r];
            s1 += v;
            s2 += v * v;
        }
        atomicAdd(&ls1[bfst * 32 + co], s1);
        atomicAdd(&ls2[bfst * 32 + co], s2);
    } else {
#pragma unroll
        for (int r = 0; r < 16; ++r) {
            const int row = (r & 3) + 8 * (r >> 2) + 4 * half;
            const int n = wbase + row;
            if (n < N) {
                const int b = batch_id[n];
                const float v = acc[r];
                atomicAdd(&ls1[b * 32 + co], v);
                atomicAdd(&ls2[b * 32 + co], v * v);
            }
        }
    }
    if (half == 0) {                 // 32 lanes per wave: one count per node
        const int n = wbase + mrow;
        if (n < N) atomicAdd(&lcnt[batch_id[n]], 1.0f);
    }
    __syncthreads();

    {
        float v;
        v = ls1[t]; if (v != 0.f) atomicAdd(&gs1[t], v);
        v = ls2[t]; if (v != 0.f) atomicAdd(&gs2[t], v);
        if (t < 8) { v = lcnt[t]; if (v != 0.f) atomicAdd(&gcnt[t], v); }
    }
}

// ---------------------------------------------------------------------------
// GN finalize + apply + ReLU (unchanged, proven)
// ---------------------------------------------------------------------------
__global__ __launch_bounds__(256) void gn_relu_kernel(
    float* __restrict__ out, const int* __restrict__ batch_id,
    const float* __restrict__ gs1, const float* __restrict__ gs2,
    const float* __restrict__ gcnt, const float* __restrict__ gamma,
    const float* __restrict__ beta, int N)
{
    const int idx = blockIdx.x * 256 + threadIdx.x;
    if (idx >= N * 8) return;
    const int n = idx >> 3;
    const int g = idx & 7;
    const int b = batch_id[n];

    const float cnt  = gcnt[b] * 4.0f;
    const float icnt = 1.0f / (cnt + EPS);
    const float4 s1 = *(const float4*)(gs1 + b * 32 + g * 4);
    const float4 s2 = *(const float4*)(gs2 + b * 32 + g * 4);
    const float S1 = s1.x + s1.y + s1.z + s1.w;
    const float S2 = s2.x + s2.y + s2.z + s2.w;
    const float m   = S1 * icnt;
    const float var = (S2 - 2.0f * m * S1 + cnt * m * m) * icnt;
    const float istd = rsqrtf(var + EPS);

    const float4 gm4 = *(const float4*)(gamma + g * 4);
    const float4 bt4 = *(const float4*)(beta + g * 4);
    float4 h = *(float4*)(out + (size_t)idx * 4);
    h.x = fmaxf((h.x - m) * istd * gm4.x + bt4.x, 0.f);
    h.y = fmaxf((h.y - m) * istd * gm4.y + bt4.y, 0.f);
    h.z = fmaxf((h.z - m) * istd * gm4.z + bt4.z, 0.f);
    h.w = fmaxf((h.w - m) * istd * gm4.w + bt4.w, 0.f);
    *(float4*)(out + (size_t)idx * 4) = h;
}

// ---------------------------------------------------------------------------
extern "C" void kernel_launch(void* const* d_in, const int* in_sizes, int n_in,
                              void* d_out, int out_size, void* d_ws, size_t ws_size,
                              hipStream_t stream) {
    const float* data     = (const float*)d_in[0];   // [N,32]
    const float* weights  = (const float*)d_in[1];   // [27,32,32]
    const float* gamma    = (const float*)d_in[2];   // [32]
    const float* beta     = (const float*)d_in[3];   // [32]
    const int*   neigh    = (const int*)d_in[4];     // [N,27]
    const int*   batch_id = (const int*)d_in[5];     // [N]
    const int N = in_sizes[0] / 32;
    float* out = (float*)d_out;

    // ws layout (bytes):
    //   [0, 2080)                      : gs1[256] gs2[256] gcnt[8] (floats)
    //   [4096, 4096+N*128)             : dpk  (N rows x 64 bf16)
    //   [.., +55296)                   : whi  (27*2*64*8 bf16)
    //   [.., +55296)                   : wlo
    char* wsb = (char*)d_ws;
    float* gs1  = (float*)wsb;
    float* gs2  = gs1 + 256;
    float* gcnt = gs1 + 512;
    unsigned short* dpk = (unsigned short*)(wsb + 4096);
    unsigned short* whi = (unsigned short*)(wsb + 4096 + (size_t)N * 128);
    unsigned short* wlo = whi + 27648;

    hipMemsetAsync(wsb, 0, 520 * sizeof(float), stream);

    hipLaunchKernelGGL(pack_data_kernel, dim3((N * 8 + 255) / 256), dim3(256),
                       0, stream, data, dpk, N);
    hipLaunchKernelGGL(pack_w_kernel, dim3(14), dim3(256), 0, stream,
                       weights, whi, wlo);

    const int nblocks = (N + 127) / 128;
    hipLaunchKernelGGL(deconv_stats_kernel, dim3(nblocks), dim3(256), 0, stream,
                       dpk, whi, wlo, neigh, batch_id, out, gs1, gs2, gcnt, N);

    const int n8 = N * 8;
    hipLaunchKernelGGL(gn_relu_kernel, dim3((n8 + 255) / 256), dim3(256), 0,
                       stream, out, batch_id, gs1, gs2, gcnt, gamma, beta, N);
}

// Round 7
// 289.388 us; speedup vs baseline: 16.5700x; 1.1189x over previous
//
#include <hip/hip_runtime.h>
#include <math.h>

#define EPS 1e-5f

typedef __attribute__((ext_vector_type(8)))  _Float16 half8;   // 8 f16 (4 VGPR)
typedef __attribute__((ext_vector_type(16))) float    floatx16;

__device__ __forceinline__ unsigned short f2h_bits(float f) {
    _Float16 h = (_Float16)f;
    return __builtin_bit_cast(unsigned short, h);
}

// ---------------------------------------------------------------------------
// Prepass A: data[N][32] fp32 -> dpk[N][32] f16 (64 B rows). thread = 4 elems
// ---------------------------------------------------------------------------
__global__ __launch_bounds__(256) void pack_data_kernel(
    const float* __restrict__ data, unsigned short* __restrict__ dpk, int N)
{
    const int i = blockIdx.x * 256 + threadIdx.x;     // float4 index
    if (i >= N * 8) return;
    const float4 v = ((const float4*)data)[i];
    ushort4 o;
    o.x = f2h_bits(v.x);
    o.y = f2h_bits(v.y);
    o.z = f2h_bits(v.z);
    o.w = f2h_bits(v.w);
    ((ushort4*)dpk)[i] = o;
}

// ---------------------------------------------------------------------------
// Prepass B: W[27][32][32] fp32 -> f16 B-fragments for mfma_f32_32x32x16_f16.
// B[k][n]: lane l holds n=l&31, k=8*(l>>5)+j. Chunk c covers ci in [16c,16c+16).
// wpk layout: [(tap*2+chunk)*64 + lane] x half8. Tap 27 = zeros (28-tap pad).
// ---------------------------------------------------------------------------
__global__ __launch_bounds__(256) void pack_w_kernel(
    const float* __restrict__ W, unsigned short* __restrict__ wpk)
{
    const int t = blockIdx.x * 256 + threadIdx.x;     // (tap*2+chunk)*64+lane
    if (t >= 28 * 2 * 64) return;
    const int l = t & 63;
    const int c = (t >> 6) & 1;
    const int k = t >> 7;
    ushort4 o0 = make_ushort4(0, 0, 0, 0), o1 = o0;
    if (k < 27) {
        const int n  = l & 31;
        const int cb = c * 16 + (l >> 5) * 8;         // ci base for this lane
        const float* wp = W + k * 1024 + n;
        o0.x = f2h_bits(wp[(cb + 0) * 32]);
        o0.y = f2h_bits(wp[(cb + 1) * 32]);
        o0.z = f2h_bits(wp[(cb + 2) * 32]);
        o0.w = f2h_bits(wp[(cb + 3) * 32]);
        o1.x = f2h_bits(wp[(cb + 4) * 32]);
        o1.y = f2h_bits(wp[(cb + 5) * 32]);
        o1.z = f2h_bits(wp[(cb + 6) * 32]);
        o1.w = f2h_bits(wp[(cb + 7) * 32]);
    }
    *(ushort4*)(wpk + (size_t)t * 8)     = o0;
    *(ushort4*)(wpk + (size_t)t * 8 + 4) = o1;
}

// ---------------------------------------------------------------------------
// Prepass C: neigh[N][27] -> neighp[N][28] (16 B-aligned rows for int4 loads)
// ---------------------------------------------------------------------------
__global__ __launch_bounds__(256) void pack_neigh_kernel(
    const int* __restrict__ neigh, int* __restrict__ neighp, int N)
{
    const int i = blockIdx.x * 256 + threadIdx.x;
    if (i >= N * 28) return;
    const int n = i / 28;
    const int k = i % 28;
    neighp[i] = neigh[n * 27 + (k < 27 ? k : 26)];
}

// ---------------------------------------------------------------------------
// Deconv via f16 MFMA + GN stats. Block = 256 = 4 waves; wave = 32 nodes x 32
// couts (one 32x32x16 acc chain, 2 MFMA per tap). B staged in LDS (57 KB,
// leaves the vector-memory address pipe entirely -- round-5's measured wall).
// A: 2 x b128 gather per lane per tap, software-pipelined one quad (4 taps)
// ahead. 28-tap loop, tap 27 has zero weights. No runtime-indexed reg arrays.
// ---------------------------------------------------------------------------
__global__ __launch_bounds__(256) void deconv_stats_kernel(
    const unsigned short* __restrict__ dpk, const unsigned short* __restrict__ wpk,
    const int* __restrict__ nbase, int nstride, int quadok,
    const int* __restrict__ batch_id, float* __restrict__ out,
    float* __restrict__ gs1, float* __restrict__ gs2, float* __restrict__ gcnt,
    int N)
{
    __shared__ unsigned short BW[28 * 2 * 64 * 8];    // 57344 B
    __shared__ float ls1[256];
    __shared__ float ls2[256];
    __shared__ float lcnt[8];

    const int t    = threadIdx.x;
    const int wv   = t >> 6;
    const int l    = t & 63;
    const int mrow = l & 31;
    const int half = l >> 5;
    const int wbase = blockIdx.x * 128 + wv * 32;
    const int node  = wbase + mrow;
    const int nc    = node < N ? node : N - 1;

    // stage all B fragments to LDS (coalesced, 14 x 4 KB)
#pragma unroll
    for (int r = 0; r < 14; ++r)
        ((int4*)BW)[r * 256 + t] = ((const int4*)wpk)[r * 256 + t];
    ls1[t] = 0.f;
    ls2[t] = 0.f;
    if (t < 8) lcnt[t] = 0.f;
    __syncthreads();

    floatx16 acc;
#pragma unroll
    for (int r = 0; r < 16; ++r) acc[r] = 0.f;

    const int* nrow = nbase + (size_t)nc * nstride;
    const int aoff  = half * 8;      // f16 offset: chunk c base = 16c + 8*half

    int4 nq;
    if (quadok) nq = ((const int4*)nrow)[0];
    else { nq.x = nrow[0]; nq.y = nrow[1]; nq.z = nrow[2]; nq.w = nrow[3]; }

    half8 a0, a1, a2, a3, a4, a5, a6, a7;     // current quad: tap j, chunk c -> a(2j+c)
    {
        const unsigned short* r0 = dpk + (size_t)nq.x * 32;
        const unsigned short* r1 = dpk + (size_t)nq.y * 32;
        const unsigned short* r2 = dpk + (size_t)nq.z * 32;
        const unsigned short* r3 = dpk + (size_t)nq.w * 32;
        a0 = *(const half8*)(r0 + aoff);  a1 = *(const half8*)(r0 + 16 + aoff);
        a2 = *(const half8*)(r1 + aoff);  a3 = *(const half8*)(r1 + 16 + aoff);
        a4 = *(const half8*)(r2 + aoff);  a5 = *(const half8*)(r2 + 16 + aoff);
        a6 = *(const half8*)(r3 + aoff);  a7 = *(const half8*)(r3 + 16 + aoff);
    }

    const half8* BL = (const half8*)BW;

#pragma unroll 1
    for (int it = 0; it < 7; ++it) {
        half8 b0, b1, b2, b3, b4, b5, b6, b7;
        if (it < 6) {                 // issue next quad's gathers (latency cover)
            int4 nqn;
            if (quadok) nqn = ((const int4*)nrow)[it + 1];
            else {
                const int kb = (it + 1) * 4;
                nqn.x = nrow[kb];
                nqn.y = nrow[kb + 1];
                nqn.z = nrow[kb + 2];
                nqn.w = nrow[kb + 3 < 27 ? kb + 3 : 26];
            }
            const unsigned short* r0 = dpk + (size_t)nqn.x * 32;
            const unsigned short* r1 = dpk + (size_t)nqn.y * 32;
            const unsigned short* r2 = dpk + (size_t)nqn.z * 32;
            const unsigned short* r3 = dpk + (size_t)nqn.w * 32;
            b0 = *(const half8*)(r0 + aoff);  b1 = *(const half8*)(r0 + 16 + aoff);
            b2 = *(const half8*)(r1 + aoff);  b3 = *(const half8*)(r1 + 16 + aoff);
            b4 = *(const half8*)(r2 + aoff);  b5 = *(const half8*)(r2 + 16 + aoff);
            b6 = *(const half8*)(r3 + aoff);  b7 = *(const half8*)(r3 + 16 + aoff);
        }

        // compute current quad: (tap*2+chunk) = 8*it + (0..7) matches a0..a7
        acc = __builtin_amdgcn_mfma_f32_32x32x16_f16(a0, BL[(8 * it + 0) * 64 + l], acc, 0, 0, 0);
        acc = __builtin_amdgcn_mfma_f32_32x32x16_f16(a1, BL[(8 * it + 1) * 64 + l], acc, 0, 0, 0);
        acc = __builtin_amdgcn_mfma_f32_32x32x16_f16(a2, BL[(8 * it + 2) * 64 + l], acc, 0, 0, 0);
        acc = __builtin_amdgcn_mfma_f32_32x32x16_f16(a3, BL[(8 * it + 3) * 64 + l], acc, 0, 0, 0);
        acc = __builtin_amdgcn_mfma_f32_32x32x16_f16(a4, BL[(8 * it + 4) * 64 + l], acc, 0, 0, 0);
        acc = __builtin_amdgcn_mfma_f32_32x32x16_f16(a5, BL[(8 * it + 5) * 64 + l], acc, 0, 0, 0);
        acc = __builtin_amdgcn_mfma_f32_32x32x16_f16(a6, BL[(8 * it + 6) * 64 + l], acc, 0, 0, 0);
        acc = __builtin_amdgcn_mfma_f32_32x32x16_f16(a7, BL[(8 * it + 7) * 64 + l], acc, 0, 0, 0);

        if (it < 6) {
            a0 = b0; a1 = b1; a2 = b2; a3 = b3;
            a4 = b4; a5 = b5; a6 = b6; a7 = b7;
        }
    }

    // ---- epilogue (round-5 proven): C layout col=l&31, row=(r&3)+8(r>>2)+4*half
    const int co = mrow;
#pragma unroll
    for (int r = 0; r < 16; ++r) {
        const int row = (r & 3) + 8 * (r >> 2) + 4 * half;
        const int n = wbase + row;
        if (n < N) out[(size_t)n * 32 + co] = acc[r];
    }

    bool fast = (wbase + 31 < N);
    int bfst = 0;
    if (fast) {
        bfst = batch_id[wbase];
        fast = (bfst == batch_id[wbase + 31]);
    }
    if (fast) {
        float s1 = 0.f, s2 = 0.f;
#pragma unroll
        for (int r = 0; r < 16; ++r) {
            const float v = acc[r];
            s1 += v;
            s2 += v * v;
        }
        atomicAdd(&ls1[bfst * 32 + co], s1);
        atomicAdd(&ls2[bfst * 32 + co], s2);
    } else {
#pragma unroll
        for (int r = 0; r < 16; ++r) {
            const int row = (r & 3) + 8 * (r >> 2) + 4 * half;
            const int n = wbase + row;
            if (n < N) {
                const int b = batch_id[n];
                const float v = acc[r];
                atomicAdd(&ls1[b * 32 + co], v);
                atomicAdd(&ls2[b * 32 + co], v * v);
            }
        }
    }
    if (half == 0) {
        const int n = wbase + mrow;
        if (n < N) atomicAdd(&lcnt[batch_id[n]], 1.0f);
    }
    __syncthreads();

    {
        float v;
        v = ls1[t]; if (v != 0.f) atomicAdd(&gs1[t], v);
        v = ls2[t]; if (v != 0.f) atomicAdd(&gs2[t], v);
        if (t < 8) { v = lcnt[t]; if (v != 0.f) atomicAdd(&gcnt[t], v); }
    }
}

// ---------------------------------------------------------------------------
// GN finalize + apply + ReLU (unchanged, proven)
// ---------------------------------------------------------------------------
__global__ __launch_bounds__(256) void gn_relu_kernel(
    float* __restrict__ out, const int* __restrict__ batch_id,
    const float* __restrict__ gs1, const float* __restrict__ gs2,
    const float* __restrict__ gcnt, const float* __restrict__ gamma,
    const float* __restrict__ beta, int N)
{
    const int idx = blockIdx.x * 256 + threadIdx.x;
    if (idx >= N * 8) return;
    const int n = idx >> 3;
    const int g = idx & 7;
    const int b = batch_id[n];

    const float cnt  = gcnt[b] * 4.0f;
    const float icnt = 1.0f / (cnt + EPS);
    const float4 s1 = *(const float4*)(gs1 + b * 32 + g * 4);
    const float4 s2 = *(const float4*)(gs2 + b * 32 + g * 4);
    const float S1 = s1.x + s1.y + s1.z + s1.w;
    const float S2 = s2.x + s2.y + s2.z + s2.w;
    const float m   = S1 * icnt;
    const float var = (S2 - 2.0f * m * S1 + cnt * m * m) * icnt;
    const float istd = rsqrtf(var + EPS);

    const float4 gm4 = *(const float4*)(gamma + g * 4);
    const float4 bt4 = *(const float4*)(beta + g * 4);
    float4 h = *(float4*)(out + (size_t)idx * 4);
    h.x = fmaxf((h.x - m) * istd * gm4.x + bt4.x, 0.f);
    h.y = fmaxf((h.y - m) * istd * gm4.y + bt4.y, 0.f);
    h.z = fmaxf((h.z - m) * istd * gm4.z + bt4.z, 0.f);
    h.w = fmaxf((h.w - m) * istd * gm4.w + bt4.w, 0.f);
    *(float4*)(out + (size_t)idx * 4) = h;
}

// ---------------------------------------------------------------------------
extern "C" void kernel_launch(void* const* d_in, const int* in_sizes, int n_in,
                              void* d_out, int out_size, void* d_ws, size_t ws_size,
                              hipStream_t stream) {
    const float* data     = (const float*)d_in[0];   // [N,32]
    const float* weights  = (const float*)d_in[1];   // [27,32,32]
    const float* gamma    = (const float*)d_in[2];   // [32]
    const float* beta     = (const float*)d_in[3];   // [32]
    const int*   neigh    = (const int*)d_in[4];     // [N,27]
    const int*   batch_id = (const int*)d_in[5];     // [N]
    const int N = in_sizes[0] / 32;
    float* out = (float*)d_out;

    // ws layout (bytes):
    //   [0, 2080)                 : gs1[256] gs2[256] gcnt[8]
    //   [4096, +N*64)             : dpk   (N x 32 f16)
    //   [.., +57344)              : wpk   (28*2*64 half8 fragments)
    //   [.., +N*112)              : neighp (N x 28 int)  -- only if ws fits
    char* wsb = (char*)d_ws;
    float* gs1  = (float*)wsb;
    float* gs2  = gs1 + 256;
    float* gcnt = gs1 + 512;
    unsigned short* dpk = (unsigned short*)(wsb + 4096);
    unsigned short* wpk = (unsigned short*)(wsb + 4096 + (size_t)N * 64);
    int* neighp = (int*)(wsb + 4096 + (size_t)N * 64 + 57344);

    const size_t need = 4096 + (size_t)N * 64 + 57344 + (size_t)N * 112;
    const int pack_ok = (ws_size >= need) ? 1 : 0;

    hipMemsetAsync(wsb, 0, 520 * sizeof(float), stream);

    hipLaunchKernelGGL(pack_data_kernel, dim3((N * 8 + 255) / 256), dim3(256),
                       0, stream, data, dpk, N);
    hipLaunchKernelGGL(pack_w_kernel, dim3(14), dim3(256), 0, stream,
                       weights, wpk);
    if (pack_ok)
        hipLaunchKernelGGL(pack_neigh_kernel, dim3((N * 28 + 255) / 256),
                           dim3(256), 0, stream, neigh, neighp, N);

    const int* nbase  = pack_ok ? neighp : neigh;
    const int nstride = pack_ok ? 28 : 27;

    const int nblocks = (N + 127) / 128;
    hipLaunchKernelGGL(deconv_stats_kernel, dim3(nblocks), dim3(256), 0, stream,
                       dpk, wpk, nbase, nstride, pack_ok, batch_id, out,
                       gs1, gs2, gcnt, N);

    const int n8 = N * 8;
    hipLaunchKernelGGL(gn_relu_kernel, dim3((n8 + 255) / 256), dim3(256), 0,
                       stream, out, batch_id, gs1, gs2, gcnt, gamma, beta, N);
}